// Round 23
// baseline (264.757 us; speedup 1.0000x reference)
//
#include <hip/hip_runtime.h>

typedef float  f32x4  __attribute__((ext_vector_type(4)));
typedef float  f32x16 __attribute__((ext_vector_type(16)));
typedef short  short8 __attribute__((ext_vector_type(8)));
typedef unsigned int uint4v __attribute__((ext_vector_type(4)));

#define LOG2E 1.4426950408889634f
#define NPIX 4096
#define CCH  512
#define DQK  64

__device__ __forceinline__ ushort f2b(float f) {
  union { float f; unsigned u; } v; v.f = f;
  unsigned r = v.u + 0x7fffu + ((v.u >> 16) & 1u);
  return (ushort)(r >> 16);
}

__device__ __forceinline__ unsigned cvt_pk_bf16(float lo, float hi) {
  unsigned r;
  asm("v_cvt_pk_bf16_f32 %0, %1, %2" : "=v"(r) : "v"(lo), "v"(hi));
  return r;
}

// in-place half-swap: a' = {a[0:32), b[0:32)}, b' = {a[32:64), b[32:64)}
__device__ __forceinline__ void plane_swap(unsigned &a, unsigned &b) {
  asm volatile("v_permlane32_swap_b32 %0, %1" : "+v"(a), "+v"(b));
}

// async 16B global -> LDS. Global src must be PER-LANE; LDS dest is
// wave-uniform base + lane*16.
__device__ __forceinline__ void gload16(const ushort* g, ushort* l) {
  __builtin_amdgcn_global_load_lds((const __attribute__((address_space(1))) void*)g,
                                   (__attribute__((address_space(3))) void*)l, 16, 0, 0);
}

// x: [B][C][N] f32  ->  Xt: [B][N][C] bf16  (tiled transpose via LDS)
__global__ __launch_bounds__(256) void k_cast_x(const float* __restrict__ x,
                                                ushort* __restrict__ Xt) {
  __shared__ float tile[32][33];
  const int b = blockIdx.z;
  const int n0 = blockIdx.x * 32, c0 = blockIdx.y * 32;
  const int t = threadIdx.x;
  {
    int cc = t >> 3, nn = (t & 7) * 4;
    const float4 v = *(const float4*)&x[((size_t)b * CCH + c0 + cc) * NPIX + n0 + nn];
    tile[cc][nn] = v.x; tile[cc][nn + 1] = v.y; tile[cc][nn + 2] = v.z; tile[cc][nn + 3] = v.w;
  }
  __syncthreads();
  {
    int nr = t >> 3, c4 = (t & 7) * 4;
    ushort4 o;
    o.x = f2b(tile[c4 + 0][nr]); o.y = f2b(tile[c4 + 1][nr]);
    o.z = f2b(tile[c4 + 2][nr]); o.w = f2b(tile[c4 + 3][nr]);
    *(ushort4*)&Xt[((size_t)b * NPIX + n0 + nr) * CCH + c0 + c4] = o;
  }
}

// pack wq(64x512), wk(64x512), wv(512x512) -> Wb[640][512] bf16
__global__ __launch_bounds__(256) void k_cast_w(const float* __restrict__ wq,
                                                const float* __restrict__ wk,
                                                const float* __restrict__ wv,
                                                ushort* __restrict__ Wb) {
  int i = blockIdx.x * 256 + threadIdx.x;
  int idx = i * 4;
  int j = idx >> 9, c = idx & 511;
  const float* src = (j < 64) ? &wq[(size_t)j * 512]
                   : (j < 128) ? &wk[(size_t)(j - 64) * 512]
                               : &wv[(size_t)(j - 128) * 512];
  float4 v = *(const float4*)&src[c];
  ushort4 o; o.x = f2b(v.x); o.y = f2b(v.y); o.z = f2b(v.z); o.w = f2b(v.w);
  *(ushort4*)&Wb[idx] = o;
}

// QKV projection GEMM: out[j,n] = sum_c Wb[j,c]*Xt[n,c] + bias[j]
// Q: fragment-order Qf[b][n32][ks:4][lane:64][e:8] (pre-scaled by LOG2E)
// K: fragment-order Kf[b][n32][ks:4][lane:64][e:8]
// V: fragment-order Vf[b][n32][c32:16][kt:2][lane:64][e:8]
__global__ __launch_bounds__(256) void k_proj(const ushort* __restrict__ Xt,
                                              const ushort* __restrict__ Wb,
                                              const float* __restrict__ bq,
                                              const float* __restrict__ bk,
                                              const float* __restrict__ bv,
                                              ushort* __restrict__ Qf,
                                              ushort* __restrict__ Kf,
                                              ushort* __restrict__ Vf) {
  __shared__ ushort Wl[64][72];
  __shared__ ushort Xl[64][72];
  const int b = blockIdx.z;
  const int n0 = blockIdx.x * 64;
  const int j0 = blockIdx.y * 64;
  const int t = threadIdx.x;
  const int w = t >> 6, l = t & 63;
  const int lr = l & 15, lq = l >> 4;
  const int wj = (w >> 1) * 32, wn = (w & 1) * 32;

  f32x4 acc[2][2];
#pragma unroll
  for (int a = 0; a < 2; ++a)
#pragma unroll
    for (int c = 0; c < 2; ++c) acc[a][c] = f32x4{0.f, 0.f, 0.f, 0.f};

  const int srow = t >> 2, sch = t & 3;
  for (int k0 = 0; k0 < 512; k0 += 64) {
    *(uint4*)&Wl[srow][sch * 8]       = *(const uint4*)&Wb[(size_t)(j0 + srow) * 512 + k0 + sch * 8];
    *(uint4*)&Wl[srow][(sch + 4) * 8] = *(const uint4*)&Wb[(size_t)(j0 + srow) * 512 + k0 + (sch + 4) * 8];
    *(uint4*)&Xl[srow][sch * 8]       = *(const uint4*)&Xt[((size_t)b * NPIX + n0 + srow) * 512 + k0 + sch * 8];
    *(uint4*)&Xl[srow][(sch + 4) * 8] = *(const uint4*)&Xt[((size_t)b * NPIX + n0 + srow) * 512 + k0 + (sch + 4) * 8];
    __syncthreads();
#pragma unroll
    for (int kt = 0; kt < 2; ++kt) {
      short8 af[2], bf[2];
#pragma unroll
      for (int jt = 0; jt < 2; ++jt)
        af[jt] = *(const short8*)&Wl[wj + jt * 16 + lr][kt * 32 + lq * 8];
#pragma unroll
      for (int nt = 0; nt < 2; ++nt)
        bf[nt] = *(const short8*)&Xl[wn + nt * 16 + lr][kt * 32 + lq * 8];
#pragma unroll
      for (int jt = 0; jt < 2; ++jt)
#pragma unroll
        for (int nt = 0; nt < 2; ++nt)
          acc[jt][nt] = __builtin_amdgcn_mfma_f32_16x16x32_bf16(af[jt], bf[nt], acc[jt][nt], 0, 0, 0);
    }
    __syncthreads();
  }

#pragma unroll
  for (int jt = 0; jt < 2; ++jt) {
    const int jb = j0 + wj + jt * 16;
#pragma unroll
    for (int nt = 0; nt < 2; ++nt) {
      const int n = n0 + wn + nt * 16 + lr;
      const int n32 = (n0 + wn) >> 5;
      if (jb < 64) {
        // Q fragment-order (same mapping as K), pre-scaled by LOG2E
        const int kd0 = jb + lq * 4;
        const int ks = jb >> 4;
        const int hl = lq >> 1;
        const int e0 = (lq * 4) & 7;
        const int lp = (nt * 16 + lr) + 32 * hl;
        ushort4 o;
        o.x = f2b(LOG2E * (acc[jt][nt][0] + bq[kd0 + 0]));
        o.y = f2b(LOG2E * (acc[jt][nt][1] + bq[kd0 + 1]));
        o.z = f2b(LOG2E * (acc[jt][nt][2] + bq[kd0 + 2]));
        o.w = f2b(LOG2E * (acc[jt][nt][3] + bq[kd0 + 3]));
        *(ushort4*)&Qf[((size_t)(b * 128 + n32) * 4 + ks) * 512 + lp * 8 + e0] = o;
      } else if (jb < 128) {
        const int kd0 = jb - 64 + lq * 4;
        const int ks = (jb - 64) >> 4;
        const int hl = lq >> 1;
        const int e0 = (lq * 4) & 7;
        const int lp = (nt * 16 + lr) + 32 * hl;
        ushort4 o;
        o.x = f2b(acc[jt][nt][0] + bk[kd0 + 0]);
        o.y = f2b(acc[jt][nt][1] + bk[kd0 + 1]);
        o.z = f2b(acc[jt][nt][2] + bk[kd0 + 2]);
        o.w = f2b(acc[jt][nt][3] + bk[kd0 + 3]);
        *(ushort4*)&Kf[((size_t)(b * 128 + n32) * 4 + ks) * 512 + lp * 8 + e0] = o;
      } else {
        const int kt = nt;
        const int hlv = (lr >> 3) & 1;
        const int e = lr & 7;
#pragma unroll
        for (int r = 0; r < 4; ++r) {
          const int c = jb - 128 + lq * 4 + r;
          Vf[(((size_t)(b * 128 + n32) * 16 + (c >> 5)) * 2 + kt) * 512 +
             (c & 31) * 8 + 256 * hlv + e] = f2b(acc[jt][nt][r] + bv[c]);
        }
      }
    }
  }
}

// flash attention v23: R20 with cross-tile phase merge — each loop segment
// does {stage K(t+2); produce P(t+1); consume P(t)} then ONE barrier.
// produce(t+1) and consume(t) touch disjoint P buffers -> waves drift within
// the segment, overlapping softmax VALU (producer) with PV MFMA (consumer)
// across waves (m114). Producer/consumer bodies identical to R20.
// 16-wave block = 128q x 512c; grid = 32qb x 8b = 256 = 1 block/CU.
__global__ __launch_bounds__(1024, 4) void k_attn(const ushort* __restrict__ Qf,
                                                  const ushort* __restrict__ Kf,
                                                  const ushort* __restrict__ Vf,
                                                  const float* __restrict__ x,
                                                  const float* __restrict__ gamma,
                                                  float* __restrict__ out) {
  __shared__ unsigned Plds[2][8][4][64][4];     // [buf][k16][q32][lane][uint4] = 64KB
  __shared__ ushort Klds[2][8192];              // [buf][g*2048 + ks*512 + lane*8] = 32KB
  __shared__ ushort Qlds[8192];                 // [q32*2048 + ks*512 + lane*8] = 16KB
  __shared__ float Lred[4][4][32];              // [q32][kg][q] partial L sums
  const int id = blockIdx.x;
  const int b  = id & 7;                        // XCD via %8 round-robin
  const int qb = id >> 3;                       // 0..31 q-strips of 128
  const int t = threadIdx.x;
  const int w = t >> 6, l = t & 63;             // w = 0..15
  const int lq = l & 31, h = l >> 5;
  const int kg = w >> 2;                        // producer key-group 0..3
  const int q32p = w & 3;                       // producer q-subtile 0..3
  const int qw = qb * 128;

  union PB { uint4v u; short8 s8; };

  const ushort* kslice = Kf + (size_t)(b * 128) * 2048;   // + tile*8192
  const ushort* vbase  = Vf + (size_t)b * 128 * 16384 + (size_t)w * 1024 + (size_t)l * 8;

  f32x16 acc[4] = {};                           // [q32] for c32 = w
  float Lp = 0.f;

  // stage K tile (1024 chunks of 16B; 1/thread; per-lane global src)
  auto stageK = [&](int buf, int tile) {
    gload16(kslice + (size_t)tile * 8192 + (size_t)(w * 64 + l) * 8, &Klds[buf][w * 512]);
  };

  // producer: QK + softmax for tile's keys [tile*128 + kg*32, +32), cols q32p;
  // writes P B-fragments for that tile into Plds[pbuf].
  auto produce = [&](int pbuf) {
    const ushort* kb = &Klds[pbuf][kg * 2048 + l * 8];
    short8 kf0 = *(const short8*)(kb);
    short8 kf1 = *(const short8*)(kb + 512);
    short8 kf2 = *(const short8*)(kb + 1024);
    short8 kf3 = *(const short8*)(kb + 1536);
    const ushort* qp = &Qlds[q32p * 2048 + l * 8];
    short8 q0 = *(const short8*)(qp);
    short8 q1 = *(const short8*)(qp + 512);
    short8 q2 = *(const short8*)(qp + 1024);
    short8 q3 = *(const short8*)(qp + 1536);
    f32x16 s = {};
    __builtin_amdgcn_s_setprio(1);
    s = __builtin_amdgcn_mfma_f32_32x32x16_bf16(kf0, q0, s, 0, 0, 0);
    s = __builtin_amdgcn_mfma_f32_32x32x16_bf16(kf1, q1, s, 0, 0, 0);
    s = __builtin_amdgcn_mfma_f32_32x32x16_bf16(kf2, q2, s, 0, 0, 0);
    s = __builtin_amdgcn_mfma_f32_32x32x16_bf16(kf3, q3, s, 0, 0, 0);
    __builtin_amdgcn_s_setprio(0);

    float sum = 0.f;
#pragma unroll
    for (int r = 0; r < 16; ++r) { s[r] = __builtin_amdgcn_exp2f(s[r]); sum += s[r]; }
    Lp += sum;
    unsigned pk0 = cvt_pk_bf16(s[0],  s[1]),  pk1 = cvt_pk_bf16(s[2],  s[3]);
    unsigned pk2 = cvt_pk_bf16(s[4],  s[5]),  pk3 = cvt_pk_bf16(s[6],  s[7]);
    unsigned pk4 = cvt_pk_bf16(s[8],  s[9]),  pk5 = cvt_pk_bf16(s[10], s[11]);
    unsigned pk6 = cvt_pk_bf16(s[12], s[13]), pk7 = cvt_pk_bf16(s[14], s[15]);
    plane_swap(pk0, pk2); plane_swap(pk1, pk3);
    plane_swap(pk4, pk6); plane_swap(pk5, pk7);
    *(uint4v*)&Plds[pbuf][kg * 2 + 0][q32p][l][0] = uint4v{pk0, pk1, pk2, pk3};
    *(uint4v*)&Plds[pbuf][kg * 2 + 1][q32p][l][0] = uint4v{pk4, pk5, pk6, pk7};
  };

  // prologue: stage Q (16KB; 1/thread), K(0), K(1); produce P(0)
  gload16(Qf + (size_t)(b * 128 + qb * 4) * 2048 + (size_t)(w * 64 + l) * 8, &Qlds[w * 512]);
  stageK(0, 0);
  stageK(1, 1);
  __syncthreads();
  produce(0);
  __syncthreads();

  for (int tile = 0; tile < 32; ++tile) {
    const int buf = tile & 1;
    if (tile + 2 < 32) stageK(buf, tile + 2);       // overwrites Klds[buf]; its
                                                    // last reader (produce(tile))
                                                    // finished before barrier(tile-1)
    if (tile + 1 < 32) produce(buf ^ 1);            // P(tile+1) -> Plds[buf^1]

    // ---- consume P(tile): batch-issue all 8 V fragment loads, PV per k16
    short8 vf[8];
#pragma unroll
    for (int k8 = 0; k8 < 8; ++k8)
      vf[k8] = *(const short8*)(vbase + (size_t)(tile * 4 + (k8 >> 1)) * 16384 +
                                (size_t)(k8 & 1) * 512);
#pragma unroll
    for (int k8 = 0; k8 < 8; ++k8) {
      PB B0, B1, B2, B3;
      B0.u = *(const uint4v*)&Plds[buf][k8][0][l][0];
      B1.u = *(const uint4v*)&Plds[buf][k8][1][l][0];
      B2.u = *(const uint4v*)&Plds[buf][k8][2][l][0];
      B3.u = *(const uint4v*)&Plds[buf][k8][3][l][0];
      __builtin_amdgcn_s_setprio(1);
      acc[0] = __builtin_amdgcn_mfma_f32_32x32x16_bf16(vf[k8], B0.s8, acc[0], 0, 0, 0);
      acc[1] = __builtin_amdgcn_mfma_f32_32x32x16_bf16(vf[k8], B1.s8, acc[1], 0, 0, 0);
      acc[2] = __builtin_amdgcn_mfma_f32_32x32x16_bf16(vf[k8], B2.s8, acc[2], 0, 0, 0);
      acc[3] = __builtin_amdgcn_mfma_f32_32x32x16_bf16(vf[k8], B3.s8, acc[3], 0, 0, 0);
      __builtin_amdgcn_s_setprio(0);
    }

    __syncthreads();   // fences: P(tile+1) visible for next iter; stage(tile+2)
                       // drained; Plds[buf] free for produce(tile+2) overwrite
  }

  // ---- L reduction across the 4 key-groups, then epilogue
  Lp += __shfl_xor(Lp, 32);
  Lred[q32p][kg][lq] = Lp;                      // both halves write same value
  __syncthreads();
  float Lt[4];
#pragma unroll
  for (int q32 = 0; q32 < 4; ++q32)
    Lt[q32] = (Lred[q32][0][lq] + Lred[q32][1][lq]) + (Lred[q32][2][lq] + Lred[q32][3][lq]);
  const float g = gamma[0];
#pragma unroll
  for (int r = 0; r < 16; ++r) {
    const int c = w * 32 + (r & 3) + 8 * (r >> 2) + 4 * h;
    const size_t base = ((size_t)b * CCH + c) * NPIX + qw + lq;
#pragma unroll
    for (int q32 = 0; q32 < 4; ++q32)
      out[base + q32 * 32] = (g / Lt[q32]) * acc[q32][r] + x[base + q32 * 32];
  }
}

extern "C" void kernel_launch(void* const* d_in, const int* in_sizes, int n_in,
                              void* d_out, int out_size, void* d_ws, size_t ws_size,
                              hipStream_t stream) {
  const float* x     = (const float*)d_in[0];
  const float* wq    = (const float*)d_in[1];
  const float* bq    = (const float*)d_in[2];
  const float* wk    = (const float*)d_in[3];
  const float* bk    = (const float*)d_in[4];
  const float* wv    = (const float*)d_in[5];
  const float* bv    = (const float*)d_in[6];
  const float* gamma = (const float*)d_in[7];
  float* out = (float*)d_out;

  // Xt (32MB bf16) lives in d_out (64MB) — dead before k_attn writes the output.
  ushort* Xt = (ushort*)d_out;
  ushort* Wb = (ushort*)d_ws;                          // 640*512
  ushort* Qf = Wb + (size_t)640 * 512;                 // 8*128*4*512 (fragment-order)
  ushort* Kf = Qf + (size_t)8 * 128 * 4 * 512;         // 8*128*4*512 (fragment-order)
  ushort* Vf = Kf + (size_t)8 * 128 * 4 * 512;         // 8*128*16*2*512 (fragment-order)
  // total ws: ~42.8 MB

  k_cast_x<<<dim3(NPIX / 32, CCH / 32, 8), 256, 0, stream>>>(x, Xt);
  k_cast_w<<<(640 * 512 / 4) / 256, 256, 0, stream>>>(wq, wk, wv, Wb);
  k_proj<<<dim3(NPIX / 64, 640 / 64, 8), 256, 0, stream>>>(Xt, Wb, bq, bk, bv, Qf, Kf, Vf);
  k_attn<<<dim3(256), 1024, 0, stream>>>(Qf, Kf, Vf, x, gamma, out);
}

// Round 24
// 234.055 us; speedup vs baseline: 1.1312x; 1.1312x over previous
//
#include <hip/hip_runtime.h>

typedef float  f32x4  __attribute__((ext_vector_type(4)));
typedef float  f32x16 __attribute__((ext_vector_type(16)));
typedef short  short8 __attribute__((ext_vector_type(8)));
typedef unsigned int uint4v __attribute__((ext_vector_type(4)));

#define LOG2E 1.4426950408889634f
#define NPIX 4096
#define CCH  512
#define DQK  64

__device__ __forceinline__ ushort f2b(float f) {
  union { float f; unsigned u; } v; v.f = f;
  unsigned r = v.u + 0x7fffu + ((v.u >> 16) & 1u);
  return (ushort)(r >> 16);
}

__device__ __forceinline__ unsigned cvt_pk_bf16(float lo, float hi) {
  unsigned r;
  asm("v_cvt_pk_bf16_f32 %0, %1, %2" : "=v"(r) : "v"(lo), "v"(hi));
  return r;
}

// in-place half-swap: a' = {a[0:32), b[0:32)}, b' = {a[32:64), b[32:64)}
__device__ __forceinline__ void plane_swap(unsigned &a, unsigned &b) {
  asm volatile("v_permlane32_swap_b32 %0, %1" : "+v"(a), "+v"(b));
}

// async 16B global -> LDS. Global src must be PER-LANE; LDS dest is
// wave-uniform base + lane*16.
__device__ __forceinline__ void gload16(const ushort* g, ushort* l) {
  __builtin_amdgcn_global_load_lds((const __attribute__((address_space(1))) void*)g,
                                   (__attribute__((address_space(3))) void*)l, 16, 0, 0);
}

// x: [B][C][N] f32  ->  Xt: [B][N][C] bf16  (tiled transpose via LDS)
__global__ __launch_bounds__(256) void k_cast_x(const float* __restrict__ x,
                                                ushort* __restrict__ Xt) {
  __shared__ float tile[32][33];
  const int b = blockIdx.z;
  const int n0 = blockIdx.x * 32, c0 = blockIdx.y * 32;
  const int t = threadIdx.x;
  {
    int cc = t >> 3, nn = (t & 7) * 4;
    const float4 v = *(const float4*)&x[((size_t)b * CCH + c0 + cc) * NPIX + n0 + nn];
    tile[cc][nn] = v.x; tile[cc][nn + 1] = v.y; tile[cc][nn + 2] = v.z; tile[cc][nn + 3] = v.w;
  }
  __syncthreads();
  {
    int nr = t >> 3, c4 = (t & 7) * 4;
    ushort4 o;
    o.x = f2b(tile[c4 + 0][nr]); o.y = f2b(tile[c4 + 1][nr]);
    o.z = f2b(tile[c4 + 2][nr]); o.w = f2b(tile[c4 + 3][nr]);
    *(ushort4*)&Xt[((size_t)b * NPIX + n0 + nr) * CCH + c0 + c4] = o;
  }
}

// pack wq(64x512), wk(64x512), wv(512x512) -> Wb[640][512] bf16
__global__ __launch_bounds__(256) void k_cast_w(const float* __restrict__ wq,
                                                const float* __restrict__ wk,
                                                const float* __restrict__ wv,
                                                ushort* __restrict__ Wb) {
  int i = blockIdx.x * 256 + threadIdx.x;
  int idx = i * 4;
  int j = idx >> 9, c = idx & 511;
  const float* src = (j < 64) ? &wq[(size_t)j * 512]
                   : (j < 128) ? &wk[(size_t)(j - 64) * 512]
                               : &wv[(size_t)(j - 128) * 512];
  float4 v = *(const float4*)&src[c];
  ushort4 o; o.x = f2b(v.x); o.y = f2b(v.y); o.z = f2b(v.z); o.w = f2b(v.w);
  *(ushort4*)&Wb[idx] = o;
}

// QKV projection GEMM: out[j,n] = sum_c Wb[j,c]*Xt[n,c] + bias[j]
// Q: fragment-order Qf[b][n32][ks:4][lane:64][e:8] (pre-scaled by LOG2E)
// K: fragment-order Kf[b][n32][ks:4][lane:64][e:8]
// V: fragment-order Vf[b][n32][c32:16][kt:2][lane:64][e:8]
__global__ __launch_bounds__(256) void k_proj(const ushort* __restrict__ Xt,
                                              const ushort* __restrict__ Wb,
                                              const float* __restrict__ bq,
                                              const float* __restrict__ bk,
                                              const float* __restrict__ bv,
                                              ushort* __restrict__ Qf,
                                              ushort* __restrict__ Kf,
                                              ushort* __restrict__ Vf) {
  __shared__ ushort Wl[64][72];
  __shared__ ushort Xl[64][72];
  const int b = blockIdx.z;
  const int n0 = blockIdx.x * 64;
  const int j0 = blockIdx.y * 64;
  const int t = threadIdx.x;
  const int w = t >> 6, l = t & 63;
  const int lr = l & 15, lq = l >> 4;
  const int wj = (w >> 1) * 32, wn = (w & 1) * 32;

  f32x4 acc[2][2];
#pragma unroll
  for (int a = 0; a < 2; ++a)
#pragma unroll
    for (int c = 0; c < 2; ++c) acc[a][c] = f32x4{0.f, 0.f, 0.f, 0.f};

  const int srow = t >> 2, sch = t & 3;
  for (int k0 = 0; k0 < 512; k0 += 64) {
    *(uint4*)&Wl[srow][sch * 8]       = *(const uint4*)&Wb[(size_t)(j0 + srow) * 512 + k0 + sch * 8];
    *(uint4*)&Wl[srow][(sch + 4) * 8] = *(const uint4*)&Wb[(size_t)(j0 + srow) * 512 + k0 + (sch + 4) * 8];
    *(uint4*)&Xl[srow][sch * 8]       = *(const uint4*)&Xt[((size_t)b * NPIX + n0 + srow) * 512 + k0 + sch * 8];
    *(uint4*)&Xl[srow][(sch + 4) * 8] = *(const uint4*)&Xt[((size_t)b * NPIX + n0 + srow) * 512 + k0 + (sch + 4) * 8];
    __syncthreads();
#pragma unroll
    for (int kt = 0; kt < 2; ++kt) {
      short8 af[2], bf[2];
#pragma unroll
      for (int jt = 0; jt < 2; ++jt)
        af[jt] = *(const short8*)&Wl[wj + jt * 16 + lr][kt * 32 + lq * 8];
#pragma unroll
      for (int nt = 0; nt < 2; ++nt)
        bf[nt] = *(const short8*)&Xl[wn + nt * 16 + lr][kt * 32 + lq * 8];
#pragma unroll
      for (int jt = 0; jt < 2; ++jt)
#pragma unroll
        for (int nt = 0; nt < 2; ++nt)
          acc[jt][nt] = __builtin_amdgcn_mfma_f32_16x16x32_bf16(af[jt], bf[nt], acc[jt][nt], 0, 0, 0);
    }
    __syncthreads();
  }

#pragma unroll
  for (int jt = 0; jt < 2; ++jt) {
    const int jb = j0 + wj + jt * 16;
#pragma unroll
    for (int nt = 0; nt < 2; ++nt) {
      const int n = n0 + wn + nt * 16 + lr;
      const int n32 = (n0 + wn) >> 5;
      if (jb < 64) {
        // Q fragment-order (same mapping as K), pre-scaled by LOG2E
        const int kd0 = jb + lq * 4;
        const int ks = jb >> 4;
        const int hl = lq >> 1;
        const int e0 = (lq * 4) & 7;
        const int lp = (nt * 16 + lr) + 32 * hl;
        ushort4 o;
        o.x = f2b(LOG2E * (acc[jt][nt][0] + bq[kd0 + 0]));
        o.y = f2b(LOG2E * (acc[jt][nt][1] + bq[kd0 + 1]));
        o.z = f2b(LOG2E * (acc[jt][nt][2] + bq[kd0 + 2]));
        o.w = f2b(LOG2E * (acc[jt][nt][3] + bq[kd0 + 3]));
        *(ushort4*)&Qf[((size_t)(b * 128 + n32) * 4 + ks) * 512 + lp * 8 + e0] = o;
      } else if (jb < 128) {
        const int kd0 = jb - 64 + lq * 4;
        const int ks = (jb - 64) >> 4;
        const int hl = lq >> 1;
        const int e0 = (lq * 4) & 7;
        const int lp = (nt * 16 + lr) + 32 * hl;
        ushort4 o;
        o.x = f2b(acc[jt][nt][0] + bk[kd0 + 0]);
        o.y = f2b(acc[jt][nt][1] + bk[kd0 + 1]);
        o.z = f2b(acc[jt][nt][2] + bk[kd0 + 2]);
        o.w = f2b(acc[jt][nt][3] + bk[kd0 + 3]);
        *(ushort4*)&Kf[((size_t)(b * 128 + n32) * 4 + ks) * 512 + lp * 8 + e0] = o;
      } else {
        const int kt = nt;
        const int hlv = (lr >> 3) & 1;
        const int e = lr & 7;
#pragma unroll
        for (int r = 0; r < 4; ++r) {
          const int c = jb - 128 + lq * 4 + r;
          Vf[(((size_t)(b * 128 + n32) * 16 + (c >> 5)) * 2 + kt) * 512 +
             (c & 31) * 8 + 256 * hlv + e] = f2b(acc[jt][nt][r] + bv[c]);
        }
      }
    }
  }
}

// flash attention v24 (= v20, best verified): 16-wave block = 128q x 512c.
// Producer: wave w makes S-subtile (kg=w>>2, q32p=w&3) from LDS-staged K/Q ->
// softmax -> P B-frags as TWO ds_write_b128 (dbuf). Barrier. Consumer: wave w
// owns c32=w x all 128q; all 8 V fragment loads batch-issued; per k8:
// 4 P ds_read_b128 + 4 PV MFMAs (acc 4x f32x16 = 64 AGPR).
// grid = 32qb x 8b = 256 = 1 block/CU = 4 waves/SIMD. LDS ~117KB.
__global__ __launch_bounds__(1024, 4) void k_attn(const ushort* __restrict__ Qf,
                                                  const ushort* __restrict__ Kf,
                                                  const ushort* __restrict__ Vf,
                                                  const float* __restrict__ x,
                                                  const float* __restrict__ gamma,
                                                  float* __restrict__ out) {
  __shared__ unsigned Plds[2][8][4][64][4];     // [buf][k16][q32][lane][uint4] = 64KB
  __shared__ ushort Klds[2][8192];              // [buf][g*2048 + ks*512 + lane*8] = 32KB
  __shared__ ushort Qlds[8192];                 // [q32*2048 + ks*512 + lane*8] = 16KB
  __shared__ float Lred[4][4][32];              // [q32][kg][q] partial L sums
  const int id = blockIdx.x;
  const int b  = id & 7;                        // XCD via %8 round-robin
  const int qb = id >> 3;                       // 0..31 q-strips of 128
  const int t = threadIdx.x;
  const int w = t >> 6, l = t & 63;             // w = 0..15
  const int lq = l & 31, h = l >> 5;
  const int kg = w >> 2;                        // producer key-group 0..3
  const int q32p = w & 3;                       // producer q-subtile 0..3
  const int qw = qb * 128;

  union PB { uint4v u; short8 s8; };

  const ushort* kslice = Kf + (size_t)(b * 128) * 2048;   // + tile*8192
  const ushort* vbase  = Vf + (size_t)b * 128 * 16384 + (size_t)w * 1024 + (size_t)l * 8;

  f32x16 acc[4] = {};                           // [q32] for c32 = w
  float Lp = 0.f;

  // stage K tile (1024 chunks of 16B; 1/thread; per-lane global src)
  auto stageK = [&](int buf, int tile) {
    gload16(kslice + (size_t)tile * 8192 + (size_t)(w * 64 + l) * 8, &Klds[buf][w * 512]);
  };

  // prologue: stage Q (128q = 4 n32 = 16KB; 1024 chunks, 1/thread) + K(0)
  gload16(Qf + (size_t)(b * 128 + qb * 4) * 2048 + (size_t)(w * 64 + l) * 8, &Qlds[w * 512]);
  stageK(0, 0);
  __syncthreads();

  for (int tile = 0; tile < 32; ++tile) {
    const int buf = tile & 1;
    if (tile + 1 < 32) stageK(buf ^ 1, tile + 1);

    // ---- producer: QK + softmax for keys [tile*128 + kg*32, +32), cols q32p
    {
      const ushort* kb = &Klds[buf][kg * 2048 + l * 8];
      short8 kf0 = *(const short8*)(kb);
      short8 kf1 = *(const short8*)(kb + 512);
      short8 kf2 = *(const short8*)(kb + 1024);
      short8 kf3 = *(const short8*)(kb + 1536);
      const ushort* qp = &Qlds[q32p * 2048 + l * 8];
      short8 q0 = *(const short8*)(qp);
      short8 q1 = *(const short8*)(qp + 512);
      short8 q2 = *(const short8*)(qp + 1024);
      short8 q3 = *(const short8*)(qp + 1536);
      f32x16 s = {};
      __builtin_amdgcn_s_setprio(1);
      s = __builtin_amdgcn_mfma_f32_32x32x16_bf16(kf0, q0, s, 0, 0, 0);
      s = __builtin_amdgcn_mfma_f32_32x32x16_bf16(kf1, q1, s, 0, 0, 0);
      s = __builtin_amdgcn_mfma_f32_32x32x16_bf16(kf2, q2, s, 0, 0, 0);
      s = __builtin_amdgcn_mfma_f32_32x32x16_bf16(kf3, q3, s, 0, 0, 0);
      __builtin_amdgcn_s_setprio(0);

      float sum = 0.f;
#pragma unroll
      for (int r = 0; r < 16; ++r) { s[r] = __builtin_amdgcn_exp2f(s[r]); sum += s[r]; }
      Lp += sum;
      unsigned pk0 = cvt_pk_bf16(s[0],  s[1]),  pk1 = cvt_pk_bf16(s[2],  s[3]);
      unsigned pk2 = cvt_pk_bf16(s[4],  s[5]),  pk3 = cvt_pk_bf16(s[6],  s[7]);
      unsigned pk4 = cvt_pk_bf16(s[8],  s[9]),  pk5 = cvt_pk_bf16(s[10], s[11]);
      unsigned pk6 = cvt_pk_bf16(s[12], s[13]), pk7 = cvt_pk_bf16(s[14], s[15]);
      plane_swap(pk0, pk2); plane_swap(pk1, pk3);
      plane_swap(pk4, pk6); plane_swap(pk5, pk7);
      *(uint4v*)&Plds[buf][kg * 2 + 0][q32p][l][0] = uint4v{pk0, pk1, pk2, pk3};
      *(uint4v*)&Plds[buf][kg * 2 + 1][q32p][l][0] = uint4v{pk4, pk5, pk6, pk7};
    }
    __syncthreads();   // drains P-writes (lgkm) + stage(t+1) (vmcnt)

    // ---- consumer: batch-issue all 8 V fragment loads, then PV per k16-slot
    short8 vf[8];
#pragma unroll
    for (int k8 = 0; k8 < 8; ++k8)
      vf[k8] = *(const short8*)(vbase + (size_t)(tile * 4 + (k8 >> 1)) * 16384 +
                                (size_t)(k8 & 1) * 512);
#pragma unroll
    for (int k8 = 0; k8 < 8; ++k8) {
      PB B0, B1, B2, B3;
      B0.u = *(const uint4v*)&Plds[buf][k8][0][l][0];
      B1.u = *(const uint4v*)&Plds[buf][k8][1][l][0];
      B2.u = *(const uint4v*)&Plds[buf][k8][2][l][0];
      B3.u = *(const uint4v*)&Plds[buf][k8][3][l][0];
      __builtin_amdgcn_s_setprio(1);
      acc[0] = __builtin_amdgcn_mfma_f32_32x32x16_bf16(vf[k8], B0.s8, acc[0], 0, 0, 0);
      acc[1] = __builtin_amdgcn_mfma_f32_32x32x16_bf16(vf[k8], B1.s8, acc[1], 0, 0, 0);
      acc[2] = __builtin_amdgcn_mfma_f32_32x32x16_bf16(vf[k8], B2.s8, acc[2], 0, 0, 0);
      acc[3] = __builtin_amdgcn_mfma_f32_32x32x16_bf16(vf[k8], B3.s8, acc[3], 0, 0, 0);
      __builtin_amdgcn_s_setprio(0);
    }
    // no trailing barrier: P dbuf ledger — produce(t+1) writes buf^1 (safe vs
    // consume(t)); produce(t+2) rewrites buf only after barrier(t+1); K stage
    // at top of t+1 rewrites Klds[t&1] only after barrier(t).
  }

  // ---- L reduction across the 4 key-groups, then epilogue
  Lp += __shfl_xor(Lp, 32);
  Lred[q32p][kg][lq] = Lp;                      // both halves write same value
  __syncthreads();
  float Lt[4];
#pragma unroll
  for (int q32 = 0; q32 < 4; ++q32)
    Lt[q32] = (Lred[q32][0][lq] + Lred[q32][1][lq]) + (Lred[q32][2][lq] + Lred[q32][3][lq]);
  const float g = gamma[0];
#pragma unroll
  for (int r = 0; r < 16; ++r) {
    const int c = w * 32 + (r & 3) + 8 * (r >> 2) + 4 * h;
    const size_t base = ((size_t)b * CCH + c) * NPIX + qw + lq;
#pragma unroll
    for (int q32 = 0; q32 < 4; ++q32)
      out[base + q32 * 32] = (g / Lt[q32]) * acc[q32][r] + x[base + q32 * 32];
  }
}

extern "C" void kernel_launch(void* const* d_in, const int* in_sizes, int n_in,
                              void* d_out, int out_size, void* d_ws, size_t ws_size,
                              hipStream_t stream) {
  const float* x     = (const float*)d_in[0];
  const float* wq    = (const float*)d_in[1];
  const float* bq    = (const float*)d_in[2];
  const float* wk    = (const float*)d_in[3];
  const float* bk    = (const float*)d_in[4];
  const float* wv    = (const float*)d_in[5];
  const float* bv    = (const float*)d_in[6];
  const float* gamma = (const float*)d_in[7];
  float* out = (float*)d_out;

  // Xt (32MB bf16) lives in d_out (64MB) — dead before k_attn writes the output.
  ushort* Xt = (ushort*)d_out;
  ushort* Wb = (ushort*)d_ws;                          // 640*512
  ushort* Qf = Wb + (size_t)640 * 512;                 // 8*128*4*512 (fragment-order)
  ushort* Kf = Qf + (size_t)8 * 128 * 4 * 512;         // 8*128*4*512 (fragment-order)
  ushort* Vf = Kf + (size_t)8 * 128 * 4 * 512;         // 8*128*16*2*512 (fragment-order)
  // total ws: ~42.8 MB

  k_cast_x<<<dim3(NPIX / 32, CCH / 32, 8), 256, 0, stream>>>(x, Xt);
  k_cast_w<<<(640 * 512 / 4) / 256, 256, 0, stream>>>(wq, wk, wv, Wb);
  k_proj<<<dim3(NPIX / 64, 640 / 64, 8), 256, 0, stream>>>(Xt, Wb, bq, bk, bv, Qf, Kf, Vf);
  k_attn<<<dim3(256), 1024, 0, stream>>>(Qf, Kf, Vf, x, gamma, out);
}

// Round 25
// 229.413 us; speedup vs baseline: 1.1541x; 1.0202x over previous
//
#include <hip/hip_runtime.h>

typedef float  f32x4  __attribute__((ext_vector_type(4)));
typedef float  f32x16 __attribute__((ext_vector_type(16)));
typedef short  short8 __attribute__((ext_vector_type(8)));
typedef unsigned int uint4v __attribute__((ext_vector_type(4)));

#define LOG2E 1.4426950408889634f
#define NPIX 4096
#define CCH  512
#define DQK  64

__device__ __forceinline__ ushort f2b(float f) {
  union { float f; unsigned u; } v; v.f = f;
  unsigned r = v.u + 0x7fffu + ((v.u >> 16) & 1u);
  return (ushort)(r >> 16);
}

__device__ __forceinline__ unsigned cvt_pk_bf16(float lo, float hi) {
  unsigned r;
  asm("v_cvt_pk_bf16_f32 %0, %1, %2" : "=v"(r) : "v"(lo), "v"(hi));
  return r;
}

// in-place half-swap: a' = {a[0:32), b[0:32)}, b' = {a[32:64), b[32:64)}
__device__ __forceinline__ void plane_swap(unsigned &a, unsigned &b) {
  asm volatile("v_permlane32_swap_b32 %0, %1" : "+v"(a), "+v"(b));
}

// async 16B global -> LDS. Global src must be PER-LANE; LDS dest is
// wave-uniform base + lane*16.
__device__ __forceinline__ void gload16(const ushort* g, ushort* l) {
  __builtin_amdgcn_global_load_lds((const __attribute__((address_space(1))) void*)g,
                                   (__attribute__((address_space(3))) void*)l, 16, 0, 0);
}

// x: [B][C][N] f32  ->  Xt: [B][N][C] bf16  (tiled transpose via LDS)
__global__ __launch_bounds__(256) void k_cast_x(const float* __restrict__ x,
                                                ushort* __restrict__ Xt) {
  __shared__ float tile[32][33];
  const int b = blockIdx.z;
  const int n0 = blockIdx.x * 32, c0 = blockIdx.y * 32;
  const int t = threadIdx.x;
  {
    int cc = t >> 3, nn = (t & 7) * 4;
    const float4 v = *(const float4*)&x[((size_t)b * CCH + c0 + cc) * NPIX + n0 + nn];
    tile[cc][nn] = v.x; tile[cc][nn + 1] = v.y; tile[cc][nn + 2] = v.z; tile[cc][nn + 3] = v.w;
  }
  __syncthreads();
  {
    int nr = t >> 3, c4 = (t & 7) * 4;
    ushort4 o;
    o.x = f2b(tile[c4 + 0][nr]); o.y = f2b(tile[c4 + 1][nr]);
    o.z = f2b(tile[c4 + 2][nr]); o.w = f2b(tile[c4 + 3][nr]);
    *(ushort4*)&Xt[((size_t)b * NPIX + n0 + nr) * CCH + c0 + c4] = o;
  }
}

// pack wq(64x512), wk(64x512), wv(512x512) -> Wb[640][512] bf16
__global__ __launch_bounds__(256) void k_cast_w(const float* __restrict__ wq,
                                                const float* __restrict__ wk,
                                                const float* __restrict__ wv,
                                                ushort* __restrict__ Wb) {
  int i = blockIdx.x * 256 + threadIdx.x;
  int idx = i * 4;
  int j = idx >> 9, c = idx & 511;
  const float* src = (j < 64) ? &wq[(size_t)j * 512]
                   : (j < 128) ? &wk[(size_t)(j - 64) * 512]
                               : &wv[(size_t)(j - 128) * 512];
  float4 v = *(const float4*)&src[c];
  ushort4 o; o.x = f2b(v.x); o.y = f2b(v.y); o.z = f2b(v.z); o.w = f2b(v.w);
  *(ushort4*)&Wb[idx] = o;
}

// QKV projection GEMM: out[j,n] = sum_c Wb[j,c]*Xt[n,c] + bias[j]
// Each block computes TWO j-tiles (j0 = y*64 and (y+5)*64) against ONE shared
// Xl stage -> Xt HBM traffic halves (320->160 MB). grid 64n x 5jp x 8b.
// Q: fragment-order Qf[b][n32][ks:4][lane:64][e:8] (pre-scaled by LOG2E)
// K: fragment-order Kf[b][n32][ks:4][lane:64][e:8]
// V: fragment-order Vf[b][n32][c32:16][kt:2][lane:64][e:8]
__global__ __launch_bounds__(256) void k_proj(const ushort* __restrict__ Xt,
                                              const ushort* __restrict__ Wb,
                                              const float* __restrict__ bq,
                                              const float* __restrict__ bk,
                                              const float* __restrict__ bv,
                                              ushort* __restrict__ Qf,
                                              ushort* __restrict__ Kf,
                                              ushort* __restrict__ Vf) {
  __shared__ ushort Wl[2][64][72];
  __shared__ ushort Xl[64][72];
  const int b = blockIdx.z;
  const int n0 = blockIdx.x * 64;
  const int jp = blockIdx.y;                    // 0..4; j-tiles jp and jp+5
  const int t = threadIdx.x;
  const int w = t >> 6, l = t & 63;
  const int lr = l & 15, lq = l >> 4;
  const int wj = (w >> 1) * 32, wn = (w & 1) * 32;

  f32x4 acc[2][2][2];                           // [jj][jt][nt]
#pragma unroll
  for (int jj = 0; jj < 2; ++jj)
#pragma unroll
    for (int a = 0; a < 2; ++a)
#pragma unroll
      for (int c = 0; c < 2; ++c) acc[jj][a][c] = f32x4{0.f, 0.f, 0.f, 0.f};

  const int srow = t >> 2, sch = t & 3;
  for (int k0 = 0; k0 < 512; k0 += 64) {
#pragma unroll
    for (int jj = 0; jj < 2; ++jj) {
      const size_t jrow = (size_t)((jp + jj * 5) * 64 + srow) * 512 + k0;
      *(uint4*)&Wl[jj][srow][sch * 8]       = *(const uint4*)&Wb[jrow + sch * 8];
      *(uint4*)&Wl[jj][srow][(sch + 4) * 8] = *(const uint4*)&Wb[jrow + (sch + 4) * 8];
    }
    *(uint4*)&Xl[srow][sch * 8]       = *(const uint4*)&Xt[((size_t)b * NPIX + n0 + srow) * 512 + k0 + sch * 8];
    *(uint4*)&Xl[srow][(sch + 4) * 8] = *(const uint4*)&Xt[((size_t)b * NPIX + n0 + srow) * 512 + k0 + (sch + 4) * 8];
    __syncthreads();
#pragma unroll
    for (int kt = 0; kt < 2; ++kt) {
      short8 bf[2];
#pragma unroll
      for (int nt = 0; nt < 2; ++nt)
        bf[nt] = *(const short8*)&Xl[wn + nt * 16 + lr][kt * 32 + lq * 8];
#pragma unroll
      for (int jj = 0; jj < 2; ++jj) {
        short8 af[2];
#pragma unroll
        for (int jt = 0; jt < 2; ++jt)
          af[jt] = *(const short8*)&Wl[jj][wj + jt * 16 + lr][kt * 32 + lq * 8];
#pragma unroll
        for (int jt = 0; jt < 2; ++jt)
#pragma unroll
          for (int nt = 0; nt < 2; ++nt)
            acc[jj][jt][nt] = __builtin_amdgcn_mfma_f32_16x16x32_bf16(af[jt], bf[nt], acc[jj][jt][nt], 0, 0, 0);
      }
    }
    __syncthreads();
  }

#pragma unroll
  for (int jj = 0; jj < 2; ++jj) {
    const int j0 = (jp + jj * 5) * 64;
#pragma unroll
    for (int jt = 0; jt < 2; ++jt) {
      const int jb = j0 + wj + jt * 16;
#pragma unroll
      for (int nt = 0; nt < 2; ++nt) {
        const int n = n0 + wn + nt * 16 + lr;
        const int n32 = (n0 + wn) >> 5;
        if (jb < 64) {
          // Q fragment-order (same mapping as K), pre-scaled by LOG2E
          const int kd0 = jb + lq * 4;
          const int ks = jb >> 4;
          const int hl = lq >> 1;
          const int e0 = (lq * 4) & 7;
          const int lp = (nt * 16 + lr) + 32 * hl;
          ushort4 o;
          o.x = f2b(LOG2E * (acc[jj][jt][nt][0] + bq[kd0 + 0]));
          o.y = f2b(LOG2E * (acc[jj][jt][nt][1] + bq[kd0 + 1]));
          o.z = f2b(LOG2E * (acc[jj][jt][nt][2] + bq[kd0 + 2]));
          o.w = f2b(LOG2E * (acc[jj][jt][nt][3] + bq[kd0 + 3]));
          *(ushort4*)&Qf[((size_t)(b * 128 + n32) * 4 + ks) * 512 + lp * 8 + e0] = o;
        } else if (jb < 128) {
          const int kd0 = jb - 64 + lq * 4;
          const int ks = (jb - 64) >> 4;
          const int hl = lq >> 1;
          const int e0 = (lq * 4) & 7;
          const int lp = (nt * 16 + lr) + 32 * hl;
          ushort4 o;
          o.x = f2b(acc[jj][jt][nt][0] + bk[kd0 + 0]);
          o.y = f2b(acc[jj][jt][nt][1] + bk[kd0 + 1]);
          o.z = f2b(acc[jj][jt][nt][2] + bk[kd0 + 2]);
          o.w = f2b(acc[jj][jt][nt][3] + bk[kd0 + 3]);
          *(ushort4*)&Kf[((size_t)(b * 128 + n32) * 4 + ks) * 512 + lp * 8 + e0] = o;
        } else {
          const int kt = nt;
          const int hlv = (lr >> 3) & 1;
          const int e = lr & 7;
#pragma unroll
          for (int r = 0; r < 4; ++r) {
            const int c = jb - 128 + lq * 4 + r;
            Vf[(((size_t)(b * 128 + n32) * 16 + (c >> 5)) * 2 + kt) * 512 +
               (c & 31) * 8 + 256 * hlv + e] = f2b(acc[jj][jt][nt][r] + bv[c]);
          }
        }
      }
    }
  }
}

// flash attention v25 (= v20, best verified): 16-wave block = 128q x 512c.
// Producer: wave w makes S-subtile (kg=w>>2, q32p=w&3) from LDS-staged K/Q ->
// softmax -> P B-frags as TWO ds_write_b128 (dbuf). Barrier. Consumer: wave w
// owns c32=w x all 128q; all 8 V fragment loads batch-issued; per k8:
// 4 P ds_read_b128 + 4 PV MFMAs (acc 4x f32x16 = 64 AGPR).
// grid = 32qb x 8b = 256 = 1 block/CU = 4 waves/SIMD. LDS ~117KB.
__global__ __launch_bounds__(1024, 4) void k_attn(const ushort* __restrict__ Qf,
                                                  const ushort* __restrict__ Kf,
                                                  const ushort* __restrict__ Vf,
                                                  const float* __restrict__ x,
                                                  const float* __restrict__ gamma,
                                                  float* __restrict__ out) {
  __shared__ unsigned Plds[2][8][4][64][4];     // [buf][k16][q32][lane][uint4] = 64KB
  __shared__ ushort Klds[2][8192];              // [buf][g*2048 + ks*512 + lane*8] = 32KB
  __shared__ ushort Qlds[8192];                 // [q32*2048 + ks*512 + lane*8] = 16KB
  __shared__ float Lred[4][4][32];              // [q32][kg][q] partial L sums
  const int id = blockIdx.x;
  const int b  = id & 7;                        // XCD via %8 round-robin
  const int qb = id >> 3;                       // 0..31 q-strips of 128
  const int t = threadIdx.x;
  const int w = t >> 6, l = t & 63;             // w = 0..15
  const int lq = l & 31, h = l >> 5;
  const int kg = w >> 2;                        // producer key-group 0..3
  const int q32p = w & 3;                       // producer q-subtile 0..3
  const int qw = qb * 128;

  union PB { uint4v u; short8 s8; };

  const ushort* kslice = Kf + (size_t)(b * 128) * 2048;   // + tile*8192
  const ushort* vbase  = Vf + (size_t)b * 128 * 16384 + (size_t)w * 1024 + (size_t)l * 8;

  f32x16 acc[4] = {};                           // [q32] for c32 = w
  float Lp = 0.f;

  // stage K tile (1024 chunks of 16B; 1/thread; per-lane global src)
  auto stageK = [&](int buf, int tile) {
    gload16(kslice + (size_t)tile * 8192 + (size_t)(w * 64 + l) * 8, &Klds[buf][w * 512]);
  };

  // prologue: stage Q (128q = 4 n32 = 16KB; 1024 chunks, 1/thread) + K(0)
  gload16(Qf + (size_t)(b * 128 + qb * 4) * 2048 + (size_t)(w * 64 + l) * 8, &Qlds[w * 512]);
  stageK(0, 0);
  __syncthreads();

  for (int tile = 0; tile < 32; ++tile) {
    const int buf = tile & 1;
    if (tile + 1 < 32) stageK(buf ^ 1, tile + 1);

    // ---- producer: QK + softmax for keys [tile*128 + kg*32, +32), cols q32p
    {
      const ushort* kb = &Klds[buf][kg * 2048 + l * 8];
      short8 kf0 = *(const short8*)(kb);
      short8 kf1 = *(const short8*)(kb + 512);
      short8 kf2 = *(const short8*)(kb + 1024);
      short8 kf3 = *(const short8*)(kb + 1536);
      const ushort* qp = &Qlds[q32p * 2048 + l * 8];
      short8 q0 = *(const short8*)(qp);
      short8 q1 = *(const short8*)(qp + 512);
      short8 q2 = *(const short8*)(qp + 1024);
      short8 q3 = *(const short8*)(qp + 1536);
      f32x16 s = {};
      __builtin_amdgcn_s_setprio(1);
      s = __builtin_amdgcn_mfma_f32_32x32x16_bf16(kf0, q0, s, 0, 0, 0);
      s = __builtin_amdgcn_mfma_f32_32x32x16_bf16(kf1, q1, s, 0, 0, 0);
      s = __builtin_amdgcn_mfma_f32_32x32x16_bf16(kf2, q2, s, 0, 0, 0);
      s = __builtin_amdgcn_mfma_f32_32x32x16_bf16(kf3, q3, s, 0, 0, 0);
      __builtin_amdgcn_s_setprio(0);

      float sum = 0.f;
#pragma unroll
      for (int r = 0; r < 16; ++r) { s[r] = __builtin_amdgcn_exp2f(s[r]); sum += s[r]; }
      Lp += sum;
      unsigned pk0 = cvt_pk_bf16(s[0],  s[1]),  pk1 = cvt_pk_bf16(s[2],  s[3]);
      unsigned pk2 = cvt_pk_bf16(s[4],  s[5]),  pk3 = cvt_pk_bf16(s[6],  s[7]);
      unsigned pk4 = cvt_pk_bf16(s[8],  s[9]),  pk5 = cvt_pk_bf16(s[10], s[11]);
      unsigned pk6 = cvt_pk_bf16(s[12], s[13]), pk7 = cvt_pk_bf16(s[14], s[15]);
      plane_swap(pk0, pk2); plane_swap(pk1, pk3);
      plane_swap(pk4, pk6); plane_swap(pk5, pk7);
      *(uint4v*)&Plds[buf][kg * 2 + 0][q32p][l][0] = uint4v{pk0, pk1, pk2, pk3};
      *(uint4v*)&Plds[buf][kg * 2 + 1][q32p][l][0] = uint4v{pk4, pk5, pk6, pk7};
    }
    __syncthreads();   // drains P-writes (lgkm) + stage(t+1) (vmcnt)

    // ---- consumer: batch-issue all 8 V fragment loads, then PV per k16-slot
    short8 vf[8];
#pragma unroll
    for (int k8 = 0; k8 < 8; ++k8)
      vf[k8] = *(const short8*)(vbase + (size_t)(tile * 4 + (k8 >> 1)) * 16384 +
                                (size_t)(k8 & 1) * 512);
#pragma unroll
    for (int k8 = 0; k8 < 8; ++k8) {
      PB B0, B1, B2, B3;
      B0.u = *(const uint4v*)&Plds[buf][k8][0][l][0];
      B1.u = *(const uint4v*)&Plds[buf][k8][1][l][0];
      B2.u = *(const uint4v*)&Plds[buf][k8][2][l][0];
      B3.u = *(const uint4v*)&Plds[buf][k8][3][l][0];
      __builtin_amdgcn_s_setprio(1);
      acc[0] = __builtin_amdgcn_mfma_f32_32x32x16_bf16(vf[k8], B0.s8, acc[0], 0, 0, 0);
      acc[1] = __builtin_amdgcn_mfma_f32_32x32x16_bf16(vf[k8], B1.s8, acc[1], 0, 0, 0);
      acc[2] = __builtin_amdgcn_mfma_f32_32x32x16_bf16(vf[k8], B2.s8, acc[2], 0, 0, 0);
      acc[3] = __builtin_amdgcn_mfma_f32_32x32x16_bf16(vf[k8], B3.s8, acc[3], 0, 0, 0);
      __builtin_amdgcn_s_setprio(0);
    }
    // no trailing barrier: P dbuf ledger — produce(t+1) writes buf^1 (safe vs
    // consume(t)); produce(t+2) rewrites buf only after barrier(t+1); K stage
    // at top of t+1 rewrites Klds[t&1] only after barrier(t).
  }

  // ---- L reduction across the 4 key-groups, then epilogue
  Lp += __shfl_xor(Lp, 32);
  Lred[q32p][kg][lq] = Lp;                      // both halves write same value
  __syncthreads();
  float Lt[4];
#pragma unroll
  for (int q32 = 0; q32 < 4; ++q32)
    Lt[q32] = (Lred[q32][0][lq] + Lred[q32][1][lq]) + (Lred[q32][2][lq] + Lred[q32][3][lq]);
  const float g = gamma[0];
#pragma unroll
  for (int r = 0; r < 16; ++r) {
    const int c = w * 32 + (r & 3) + 8 * (r >> 2) + 4 * h;
    const size_t base = ((size_t)b * CCH + c) * NPIX + qw + lq;
#pragma unroll
    for (int q32 = 0; q32 < 4; ++q32)
      out[base + q32 * 32] = (g / Lt[q32]) * acc[q32][r] + x[base + q32 * 32];
  }
}

extern "C" void kernel_launch(void* const* d_in, const int* in_sizes, int n_in,
                              void* d_out, int out_size, void* d_ws, size_t ws_size,
                              hipStream_t stream) {
  const float* x     = (const float*)d_in[0];
  const float* wq    = (const float*)d_in[1];
  const float* bq    = (const float*)d_in[2];
  const float* wk    = (const float*)d_in[3];
  const float* bk    = (const float*)d_in[4];
  const float* wv    = (const float*)d_in[5];
  const float* bv    = (const float*)d_in[6];
  const float* gamma = (const float*)d_in[7];
  float* out = (float*)d_out;

  // Xt (32MB bf16) lives in d_out (64MB) — dead before k_attn writes the output.
  ushort* Xt = (ushort*)d_out;
  ushort* Wb = (ushort*)d_ws;                          // 640*512
  ushort* Qf = Wb + (size_t)640 * 512;                 // 8*128*4*512 (fragment-order)
  ushort* Kf = Qf + (size_t)8 * 128 * 4 * 512;         // 8*128*4*512 (fragment-order)
  ushort* Vf = Kf + (size_t)8 * 128 * 4 * 512;         // 8*128*16*2*512 (fragment-order)
  // total ws: ~42.8 MB

  k_cast_x<<<dim3(NPIX / 32, CCH / 32, 8), 256, 0, stream>>>(x, Xt);
  k_cast_w<<<(640 * 512 / 4) / 256, 256, 0, stream>>>(wq, wk, wv, Wb);
  k_proj<<<dim3(NPIX / 64, 5, 8), 256, 0, stream>>>(Xt, Wb, bq, bk, bv, Qf, Kf, Vf);
  k_attn<<<dim3(256), 1024, 0, stream>>>(Qf, Kf, Vf, x, gamma, out);
}